// Round 3
// baseline (446.218 us; speedup 1.0000x reference)
//
#include <hip/hip_runtime.h>
#include <math.h>

#define HDIM 256
#define NATT 100
#define NPAD 112   // W_at rows padded to 7 tiles of 16
#define PSTR 260   // proj LDS row stride (floats)

typedef __attribute__((ext_vector_type(8))) short short8v;
typedef __attribute__((ext_vector_type(4))) float f32x4;

static __device__ __forceinline__ unsigned short f2bf(float x) {
    union { float f; unsigned u; } v; v.f = x;
    const unsigned r = v.u + 0x7FFFu + ((v.u >> 16) & 1u);
    return (unsigned short)(r >> 16);
}
static __device__ __forceinline__ float bf2f(unsigned short s) {
    union { float f; unsigned u; } v; v.u = ((unsigned)s) << 16;
    return v.f;
}

// ---------------------------------------------------------------------------
// prep (24 blocks x 256):
//  blk0 : wcm + consts[0] + zero stats_acc      blk1: wcc + consts[1]
//  blk2,3: m2m + consts[2,3]                    blk4,5: m2c + consts[4,5]
//  blk6..15 : canonical split-bf16 first-layer weights Wc[m*2+x][h][32]
//             (m: 0=W_a,1=W_i,2=W_iC,3=W_e,4=W_eC; x: 0=J-half,1=I-half)
//             feature order k0..15 = [zd0,zd1,zc0..11,zm,zc], k16 = bias slot
//  blk16..23: W_at split-bf16, rows padded to 112
// ---------------------------------------------------------------------------
__launch_bounds__(256)
__global__ void prep_kernel(
    const float* __restrict__ Ws1, const float* __restrict__ bs1,
    const float* __restrict__ Ws2, const float* __restrict__ bs2,
    const float* __restrict__ Ws1C, const float* __restrict__ bs1C,
    const float* __restrict__ Ws2C, const float* __restrict__ bs2C,
    const float* __restrict__ W2,  const float* __restrict__ b2,
    const float* __restrict__ Wd,
    const float* __restrict__ W2C, const float* __restrict__ b2C,
    const float* __restrict__ WdC,
    const float* __restrict__ W_at,
    const float* __restrict__ W_a,  const float* __restrict__ b_a,
    const float* __restrict__ W_i,  const float* __restrict__ b_i,
    const float* __restrict__ W_iC, const float* __restrict__ b_iC,
    const float* __restrict__ W_e,  const float* __restrict__ b_e,
    const float* __restrict__ W_eC, const float* __restrict__ b_eC,
    float* __restrict__ wcm, float* __restrict__ wcc,
    float* __restrict__ m2m, float* __restrict__ m2c,
    float* __restrict__ consts, float* __restrict__ stats_acc,
    unsigned short* __restrict__ Wh, unsigned short* __restrict__ Wl,
    unsigned short* __restrict__ WcH, unsigned short* __restrict__ WcL)
{
    const int h = threadIdx.x;
    const int blk = blockIdx.x;
    if (blk == 0) {
        float a = 0.f;
        for (int k = 0; k < HDIM; ++k) a += Ws2[k] * Ws1[k*HDIM + h];
        wcm[h] = a;
        if (h == 0) {
            float bsum = bs2[0];
            for (int k = 0; k < HDIM; ++k) bsum += Ws2[k] * bs1[k];
            consts[0] = bsum;
            stats_acc[0] = 0.f; stats_acc[1] = 0.f;
            stats_acc[2] = 0.f; stats_acc[3] = 0.f;
        }
    } else if (blk == 1) {
        float a = 0.f;
        for (int k = 0; k < HDIM; ++k) a += Ws2C[k] * Ws1C[k*HDIM + h];
        wcc[h] = a;
        if (h == 0) {
            float bsum = bs2C[0];
            for (int k = 0; k < HDIM; ++k) bsum += Ws2C[k] * bs1C[k];
            consts[1] = bsum;
        }
    } else if (blk < 4) {
        const int c = blk - 2;
        float a = 0.f;
        for (int k = 0; k < HDIM; ++k) a += Wd[c*HDIM + k] * W2[k*HDIM + h];
        m2m[c*HDIM + h] = a;
        if (h == 0) {
            float bsum = 0.f;
            for (int k = 0; k < HDIM; ++k) bsum += Wd[c*HDIM + k] * b2[k];
            consts[2 + c] = bsum;
        }
    } else if (blk < 6) {
        const int c = blk - 4;
        float a = 0.f;
        for (int k = 0; k < HDIM; ++k) a += WdC[c*HDIM + k] * W2C[k*HDIM + h];
        m2c[c*HDIM + h] = a;
        if (h == 0) {
            float bsum = 0.f;
            for (int k = 0; k < HDIM; ++k) bsum += WdC[c*HDIM + k] * b2C[k];
            consts[4 + c] = bsum;
        }
    } else if (blk < 16) {
        const int q = blk - 6;          // m*2 + x
        const int m = q >> 1, x = q & 1;
        const float* W; const float* bias; int type;
        switch (m) {
            case 0:  W = W_a;  bias = b_a;  type = 0; break;
            case 1:  W = W_i;  bias = b_i;  type = 1; break;
            case 2:  W = W_iC; bias = b_iC; type = 2; break;
            case 3:  W = W_e;  bias = b_e;  type = 0; break;
            default: W = W_eC; bias = b_eC; type = 2; break;
        }
        float tmp[32];
        #pragma unroll
        for (int k = 0; k < 32; ++k) tmp[k] = 0.f;
        if (type == 0) {                 // x_12 cd layout: 28 cols
            const float* row = W + h*28 + x*14;
            for (int k = 0; k < 14; ++k) tmp[k] = row[k];
        } else if (type == 1) {          // f_12: [zm, cd] per half: 30 cols
            const float* row = W + h*30 + x*15;
            tmp[14] = row[0];
            for (int k = 0; k < 14; ++k) tmp[k] = row[1+k];
        } else {                         // fc_12: [ct_j ct_i zc_j zc_i v_j v_i]
            const float* row = W + h*30;
            for (int k = 0; k < 12; ++k) tmp[2+k] = row[x*12 + k];
            tmp[15] = row[24 + x];
            tmp[0] = row[26 + x*2];
            tmp[1] = row[27 + x*2];
        }
        tmp[16] = 0.5f * bias[h];
        const int base = (q*HDIM + h)*32;
        for (int k = 0; k < 32; ++k) {
            const unsigned short hi = f2bf(tmp[k]);
            WcH[base + k] = hi;
            WcL[base + k] = f2bf(tmp[k] - bf2f(hi));
        }
    } else {
        const int rbase = (blk - 16) * 14;
        for (int rr = 0; rr < 14; ++rr) {
            const int row = rbase + rr;
            const float v = (row < NATT) ? W_at[row*HDIM + h] : 0.f;
            const unsigned short hi = f2bf(v);
            Wh[row*HDIM + h] = hi;
            Wl[row*HDIM + h] = f2bf(v - bf2f(hi));
        }
    }
}

// ---------------------------------------------------------------------------
// main: one block (4 waves) per scene. All GEMM-shaped work on MFMA.
// ---------------------------------------------------------------------------
__launch_bounds__(256, 4)
__global__ void main_kernel(
    const float* __restrict__ z_dyn, const float* __restrict__ z_contex,
    const float* __restrict__ z_mc,
    const float* __restrict__ b_at,
    const float* __restrict__ W_at2, const float* __restrict__ b_at2,
    const unsigned short* __restrict__ Wh, const unsigned short* __restrict__ Wl,
    const unsigned short* __restrict__ WcH, const unsigned short* __restrict__ WcL,
    const float* __restrict__ wcm,  const float* __restrict__ wcc,
    const float* __restrict__ m2m,  const float* __restrict__ m2c,
    const float* __restrict__ consts,
    float* __restrict__ pm_g, float* __restrict__ s_g, float* __restrict__ sC_g,
    float* __restrict__ um_g, float* __restrict__ uc_g,
    float* __restrict__ stats_acc)
{
    __shared__ float s_in[8][16];
    alignas(16) __shared__ float proj[16][PSTR];   // rows 0..7 J-half, 8..15 I-half
    alignas(16) __shared__ float AccE[8][PSTR];
    alignas(16) __shared__ float AccC[8][PSTR];
    __shared__ float pm_t[64];                     // [j][i]
    __shared__ float pmsum_s[8];
    __shared__ float ss_s[64];
    __shared__ float sc_s[64];
    __shared__ float y_s[32];

    const int tid  = threadIdx.x;
    const int b    = blockIdx.x;
    const int lane = tid & 63;
    const int lw   = tid >> 6;       // wave id
    const int lr   = lane & 15;
    const int lq   = lane >> 4;      // 0..3

    // ---- Ph0: load scene inputs ----
    if (tid < 128) {
        const int o = tid >> 4, c = tid & 15;
        const int tok = b*8 + o;
        float v;
        if (c < 2)       v = z_dyn[tok*2 + c];
        else if (c < 14) v = z_contex[tok*12 + (c-2)];
        else             v = z_mc[tok*2 + (c-14)];
        s_in[o][c] = v;
    }
    __syncthreads();

    // ---- feature B-fragment (held in VGPRs for all 5 projections) ----
    // B[k][col=obj]: lane holds obj=lr, k = lq*8+e; k16 = 1 (bias), k>16 = 0
    short8v bfh, bfl;
    #pragma unroll
    for (int e = 0; e < 8; ++e) {
        const int k = lq*8 + e;
        float f = 0.f;
        if (lr < 8) f = (k < 16) ? s_in[lr][k] : (k == 16 ? 1.0f : 0.f);
        const unsigned short h16 = f2bf(f);
        bfh[e] = (short)h16;
        bfl[e] = (short)f2bf(f - bf2f(h16));
    }

    // projection macro: D[h][obj] = Wc[m] @ feat^T, 3-pass split-bf16.
    // jobs: 2 halves x 16 h-tiles = 32; 8 per wave.
#define PROJECT(MIDX)                                                          \
    {                                                                          \
        const int mb = (MIDX)*2*HDIM*32;                                       \
        _Pragma("unroll")                                                      \
        for (int jj = 0; jj < 8; ++jj) {                                       \
            const int job = lw*8 + jj;                                         \
            const int x = job >> 4, t = job & 15;                              \
            const int off = mb + ((x*HDIM) + t*16 + lr)*32 + lq*8;             \
            const short8v ah = *(const short8v*)&WcH[off];                     \
            const short8v al = *(const short8v*)&WcL[off];                     \
            f32x4 d = (f32x4){0.f, 0.f, 0.f, 0.f};                             \
            d = __builtin_amdgcn_mfma_f32_16x16x32_bf16(ah, bfh, d, 0, 0, 0);  \
            d = __builtin_amdgcn_mfma_f32_16x16x32_bf16(al, bfh, d, 0, 0, 0);  \
            d = __builtin_amdgcn_mfma_f32_16x16x32_bf16(ah, bfl, d, 0, 0, 0);  \
            if (lr < 8) *(f32x4*)&proj[x*8 + lr][t*16 + lq*4] = d;             \
        }                                                                      \
    }                                                                          \
    __syncthreads();

    // ================= m=0: W_a -> presents (Ph2) =================
    PROJECT(0)
    {
        const int pA = 16*lw + lr;          // pair for this lane's A-row
        const int jA = pA & 7, iA = pA >> 3;
        f32x4 acc[7];
        #pragma unroll
        for (int n = 0; n < 7; ++n) acc[n] = (f32x4){0.f, 0.f, 0.f, 0.f};

        #pragma unroll 2
        for (int k = 0; k < 8; ++k) {
            const int kb = k*32 + lq*8;
            const float4 vj0 = *(const float4*)&proj[jA][kb];
            const float4 vj1 = *(const float4*)&proj[jA][kb+4];
            const float4 vi0 = *(const float4*)&proj[8+iA][kb];
            const float4 vi1 = *(const float4*)&proj[8+iA][kb+4];
            float v[8] = {vj0.x+vi0.x, vj0.y+vi0.y, vj0.z+vi0.z, vj0.w+vi0.w,
                          vj1.x+vi1.x, vj1.y+vi1.y, vj1.z+vi1.z, vj1.w+vi1.w};
            short8v ah, al;
            #pragma unroll
            for (int e = 0; e < 8; ++e) {
                const float r = fmaxf(v[e], 0.f);
                const unsigned short h16 = f2bf(r);
                ah[e] = (short)h16;
                al[e] = (short)f2bf(r - bf2f(h16));
            }
            #pragma unroll
            for (int n = 0; n < 7; ++n) {
                const int a = 16*n + lr;
                const short8v bh = *(const short8v*)&Wh[a*HDIM + kb];
                const short8v bl = *(const short8v*)&Wl[a*HDIM + kb];
                acc[n] = __builtin_amdgcn_mfma_f32_16x16x32_bf16(ah, bh, acc[n], 0, 0, 0);
                acc[n] = __builtin_amdgcn_mfma_f32_16x16x32_bf16(al, bh, acc[n], 0, 0, 0);
                acc[n] = __builtin_amdgcn_mfma_f32_16x16x32_bf16(ah, bl, acc[n], 0, 0, 0);
            }
        }
        float part[4] = {0.f, 0.f, 0.f, 0.f};
        #pragma unroll
        for (int n = 0; n < 7; ++n) {
            const int a = 16*n + lr;
            if (a < NATT) {
                const float bat = b_at[a], wat2 = W_at2[a];
                #pragma unroll
                for (int r = 0; r < 4; ++r)
                    part[r] += wat2 * tanhf(acc[n][r] + bat);
            }
        }
        #pragma unroll
        for (int r = 0; r < 4; ++r) {
            float s = part[r];
            s += __shfl_xor(s, 1); s += __shfl_xor(s, 2);
            s += __shfl_xor(s, 4); s += __shfl_xor(s, 8);
            part[r] = s;
        }
        if (lr == 0) {
            const float b2v = b_at2[0];
            #pragma unroll
            for (int r = 0; r < 4; ++r) {
                const int p = 16*lw + 4*lq + r;     // D row = pair
                const int ip = p >> 3, jp = p & 7;
                const float pres = 1.f / (1.f + expf(-(part[r] + b2v)));
                const float pmv = (ip != jp) ? pres : 0.f;
                pm_t[jp*8 + ip] = pmv;
                pm_g[b*64 + jp*8 + ip] = pmv;
            }
        }
    }
    __syncthreads();

    // ================= m=1: W_i -> s (dot with wcm) =================
    if (tid < 8) {
        float su = 0.f;
        #pragma unroll
        for (int i = 0; i < 8; ++i) su += pm_t[tid*8 + i];
        pmsum_s[tid] = su;
    }
    PROJECT(1)
    {
        const int p = tid >> 2, l2 = tid & 3;
        const int ip = p >> 3, jp = p & 7;
        float a = 0.f;
        #pragma unroll
        for (int u = 0; u < 16; ++u) {
            const int h4 = (l2*16 + u) * 4;
            const float4 aj = *(const float4*)&proj[jp][h4];
            const float4 ai = *(const float4*)&proj[8+ip][h4];
            const float4 wv = *(const float4*)&wcm[h4];
            a += wv.x*fmaxf(aj.x+ai.x, 0.f) + wv.y*fmaxf(aj.y+ai.y, 0.f)
               + wv.z*fmaxf(aj.z+ai.z, 0.f) + wv.w*fmaxf(aj.w+ai.w, 0.f);
        }
        a += __shfl_xor(a, 1); a += __shfl_xor(a, 2);
        if (l2 == 0) {
            const float sv = a + consts[0];
            ss_s[p] = sv;
            s_g[b*64 + jp*8 + ip] = sv;
        }
    }
    __syncthreads();

    // ================= m=2: W_iC -> sC (dot with wcc) =================
    PROJECT(2)
    {
        const int p = tid >> 2, l2 = tid & 3;
        const int ip = p >> 3, jp = p & 7;
        float a = 0.f;
        #pragma unroll
        for (int u = 0; u < 16; ++u) {
            const int h4 = (l2*16 + u) * 4;
            const float4 aj = *(const float4*)&proj[jp][h4];
            const float4 ai = *(const float4*)&proj[8+ip][h4];
            const float4 wv = *(const float4*)&wcc[h4];
            a += wv.x*fmaxf(aj.x+ai.x, 0.f) + wv.y*fmaxf(aj.y+ai.y, 0.f)
               + wv.z*fmaxf(aj.z+ai.z, 0.f) + wv.w*fmaxf(aj.w+ai.w, 0.f);
        }
        a += __shfl_xor(a, 1); a += __shfl_xor(a, 2);
        if (l2 == 0) {
            const float sv = a + consts[1];
            sc_s[p] = sv;
            sC_g[b*64 + jp*8 + ip] = sv;
        }
    }
    __syncthreads();

    // ================= m=3: W_e -> AccE (pm-weighted) + stats atomics ======
    if (tid < 64) {
        const float v1 = ss_s[tid], v2 = sc_s[tid];
        float a0 = v1, a1 = v1*v1, a2 = v2, a3 = v2*v2;
        #pragma unroll
        for (int mm = 1; mm < 64; mm <<= 1) {
            a0 += __shfl_xor(a0, mm); a1 += __shfl_xor(a1, mm);
            a2 += __shfl_xor(a2, mm); a3 += __shfl_xor(a3, mm);
        }
        if (tid == 0) {
            atomicAdd(&stats_acc[0], a0); atomicAdd(&stats_acc[1], a1);
            atomicAdd(&stats_acc[2], a2); atomicAdd(&stats_acc[3], a3);
        }
    }
    PROJECT(3)
    {
        const int h = tid;
        float Pj[8], Pi[8];
        #pragma unroll
        for (int o = 0; o < 8; ++o) { Pj[o] = proj[o][h]; Pi[o] = proj[8+o][h]; }
        #pragma unroll
        for (int j = 0; j < 8; ++j) {
            const float4 pm0 = *(const float4*)&pm_t[j*8];
            const float4 pm1 = *(const float4*)&pm_t[j*8 + 4];
            const float pjv = Pj[j];
            float a = pm0.x*fmaxf(pjv+Pi[0],0.f) + pm0.y*fmaxf(pjv+Pi[1],0.f)
                    + pm0.z*fmaxf(pjv+Pi[2],0.f) + pm0.w*fmaxf(pjv+Pi[3],0.f)
                    + pm1.x*fmaxf(pjv+Pi[4],0.f) + pm1.y*fmaxf(pjv+Pi[5],0.f)
                    + pm1.z*fmaxf(pjv+Pi[6],0.f) + pm1.w*fmaxf(pjv+Pi[7],0.f);
            AccE[j][h] = a;
        }
    }
    __syncthreads();

    // ================= m=4: W_eC -> AccC (mask-weighted) =================
    PROJECT(4)
    {
        const int h = tid;
        float Pj[8], Pi[8];
        #pragma unroll
        for (int o = 0; o < 8; ++o) { Pj[o] = proj[o][h]; Pi[o] = proj[8+o][h]; }
        #pragma unroll
        for (int j = 0; j < 8; ++j) {
            const float pjv = Pj[j];
            float a = 0.f;
            #pragma unroll
            for (int i = 0; i < 8; ++i)
                a += (i != j) ? fmaxf(pjv + Pi[i], 0.f) : 0.f;
            AccC[j][h] = a;
        }
    }
    __syncthreads();

    // ---- Ph5: y = M2 @ Acc + pmsum*bd ; u = y / max(||y||,1e-12) ----
    {
        const int t = tid >> 3, l3 = tid & 7;       // 32 tasks x 8 lanes
        const int type = t >> 4, c = (t >> 3) & 1, jj = t & 7;
        const float* M2 = type ? m2c : m2m;
        const float (*Acc)[PSTR] = type ? AccC : AccE;
        float a = 0.f;
        #pragma unroll
        for (int u = 0; u < 8; ++u) {
            const int h4 = l3*32 + u*4;
            const float4 mv = *(const float4*)&M2[c*256 + h4];
            const float4 av = *(const float4*)&Acc[jj][h4];
            a += mv.x*av.x + mv.y*av.y + mv.z*av.z + mv.w*av.w;
        }
        a += __shfl_xor(a, 1); a += __shfl_xor(a, 2); a += __shfl_xor(a, 4);
        if (l3 == 0) {
            const float bd = consts[2 + type*2 + c];
            const float pms = type ? 7.0f : pmsum_s[jj];
            y_s[t] = a + pms * bd;
        }
    }
    __syncthreads();
    if (tid < 16) {
        const int type = tid >> 3, j = tid & 7;
        const float y0 = y_s[type*16 + j];
        const float y1 = y_s[type*16 + 8 + j];
        const float n = fmaxf(sqrtf(y0*y0 + y1*y1), 1e-12f);
        float* u = type ? uc_g : um_g;
        u[(b*8 + j)*2 + 0] = y0 / n;
        u[(b*8 + j)*2 + 1] = y1 / n;
    }
#undef PROJECT
}

// ---------------------------------------------------------------------------
// final: derive batchnorm affine from global sums, then
//        scale = sum_i softplus(norm(s))*w ; out = scale*u
// ---------------------------------------------------------------------------
__launch_bounds__(256)
__global__ void final_kernel(const float* __restrict__ s_g, const float* __restrict__ sC_g,
                             const float* __restrict__ pm_g,
                             const float* __restrict__ um_g, const float* __restrict__ uc_g,
                             const float* __restrict__ stats_acc,
                             const float* __restrict__ gM, const float* __restrict__ beM,
                             const float* __restrict__ gC, const float* __restrict__ beC,
                             float* __restrict__ out, int ntok, float inv_n)
{
    const int t = blockIdx.x * blockDim.x + threadIdx.x;
    if (t >= ntok) return;
    const int j = t & 7;
    float mean = stats_acc[0] * inv_n;
    float var  = stats_acc[1] * inv_n - mean*mean;
    const float kM = gM[0] / sqrtf(var + 1e-5f);
    const float cM = beM[0] - mean*kM;
    mean = stats_acc[2] * inv_n;
    var  = stats_acc[3] * inv_n - mean*mean;
    const float kC = gC[0] / sqrtf(var + 1e-5f);
    const float cC = beC[0] - mean*kC;

    const float4 sa = *(const float4*)&s_g[t*8];
    const float4 sb = *(const float4*)&s_g[t*8 + 4];
    const float4 ca = *(const float4*)&sC_g[t*8];
    const float4 cb = *(const float4*)&sC_g[t*8 + 4];
    const float4 pa = *(const float4*)&pm_g[t*8];
    const float4 pb = *(const float4*)&pm_g[t*8 + 4];
    const float sv[8] = {sa.x,sa.y,sa.z,sa.w, sb.x,sb.y,sb.z,sb.w};
    const float cv[8] = {ca.x,ca.y,ca.z,ca.w, cb.x,cb.y,cb.z,cb.w};
    const float pv[8] = {pa.x,pa.y,pa.z,pa.w, pb.x,pb.y,pb.z,pb.w};
    float sc = 0.f, scC = 0.f, spj = 0.f;
    #pragma unroll
    for (int i = 0; i < 8; ++i) {
        const float sn = sv[i]*kM + cM;
        const float sp = fmaxf(sn, 0.f) + log1pf(expf(-fabsf(sn)));
        sc += sp * pv[i];
        const float snc = cv[i]*kC + cC;
        const float spc = fmaxf(snc, 0.f) + log1pf(expf(-fabsf(snc)));
        scC += spc;
        if (i == j) spj = spc;
    }
    scC -= spj;
    const float2 u_m = *(const float2*)&um_g[t*2];
    const float2 u_c = *(const float2*)&uc_g[t*2];
    const float m0 = sc  * u_m.x, m1 = sc  * u_m.y;
    const float c0 = scC * u_c.x, c1 = scC * u_c.y;
    *(float2*)&out[t*2]          = make_float2(m0 + c0, m1 + c1);
    *(float2*)&out[ntok*2 + t*2] = make_float2(m0, m1);
    *(float2*)&out[ntok*4 + t*2] = make_float2(c0, c1);
}

extern "C" void kernel_launch(void* const* d_in, const int* in_sizes, int n_in,
                              void* d_out, int out_size, void* d_ws, size_t ws_size,
                              hipStream_t stream) {
    const float* z_dyn    = (const float*)d_in[0];
    const float* z_contex = (const float*)d_in[1];
    const float* z_mc     = (const float*)d_in[2];
    const float* W_e   = (const float*)d_in[3];  const float* b_e   = (const float*)d_in[4];
    const float* W_i   = (const float*)d_in[5];  const float* b_i   = (const float*)d_in[6];
    const float* W_a   = (const float*)d_in[7];  const float* b_a   = (const float*)d_in[8];
    const float* W_2   = (const float*)d_in[9];  const float* b_2   = (const float*)d_in[10];
    const float* W_at  = (const float*)d_in[11]; const float* b_at  = (const float*)d_in[12];
    const float* W_at2 = (const float*)d_in[13]; const float* b_at2 = (const float*)d_in[14];
    const float* W_s1  = (const float*)d_in[15]; const float* b_s1  = (const float*)d_in[16];
    const float* W_s2  = (const float*)d_in[17]; const float* b_s2  = (const float*)d_in[18];
    const float* W_eC  = (const float*)d_in[19]; const float* b_eC  = (const float*)d_in[20];
    const float* W_iC  = (const float*)d_in[21]; const float* b_iC  = (const float*)d_in[22];
    const float* W_2C  = (const float*)d_in[23]; const float* b_2C  = (const float*)d_in[24];
    const float* W_s1C = (const float*)d_in[25]; const float* b_s1C = (const float*)d_in[26];
    const float* W_s2C = (const float*)d_in[27]; const float* b_s2C = (const float*)d_in[28];
    const float* g_M   = (const float*)d_in[29]; const float* be_M  = (const float*)d_in[30];
    const float* g_C   = (const float*)d_in[31]; const float* be_C  = (const float*)d_in[32];
    const float* W_d   = (const float*)d_in[33];
    const float* W_dC  = (const float*)d_in[34];

    const int ntok = in_sizes[0] / 2;   // 16384
    const int B = ntok / 8;             // 2048

    float* ws = (float*)d_ws;
    float* pm_g   = ws;                  // B*64 ([b][j][i])
    float* s_g    = pm_g + B*64;         // B*64
    float* sC_g   = s_g  + B*64;         // B*64
    float* um_g   = sC_g + B*64;         // ntok*2
    float* uc_g   = um_g + ntok*2;       // ntok*2
    float* wcm    = uc_g + ntok*2;       // 256
    float* wcc    = wcm + 256;           // 256
    float* m2m    = wcc + 256;           // 512
    float* m2c    = m2m + 512;           // 512
    float* consts = m2c + 512;           // 8
    float* stats_acc = consts + 8;       // 4
    unsigned short* Wh  = (unsigned short*)(stats_acc + 4);  // NPAD*HDIM
    unsigned short* Wl  = Wh + NPAD*HDIM;
    unsigned short* WcH = Wl + NPAD*HDIM;                    // 10*HDIM*32
    unsigned short* WcL = WcH + 10*HDIM*32;

    prep_kernel<<<24, 256, 0, stream>>>(
        W_s1, b_s1, W_s2, b_s2, W_s1C, b_s1C, W_s2C, b_s2C,
        W_2, b_2, W_d, W_2C, b_2C, W_dC, W_at,
        W_a, b_a, W_i, b_i, W_iC, b_iC, W_e, b_e, W_eC, b_eC,
        wcm, wcc, m2m, m2c, consts, stats_acc, Wh, Wl, WcH, WcL);

    main_kernel<<<B, 256, 0, stream>>>(
        z_dyn, z_contex, z_mc,
        b_at, W_at2, b_at2,
        Wh, Wl, WcH, WcL,
        wcm, wcc, m2m, m2c, consts,
        pm_g, s_g, sC_g, um_g, uc_g, stats_acc);

    final_kernel<<<(ntok + 255)/256, 256, 0, stream>>>(
        s_g, sC_g, pm_g, um_g, uc_g, stats_acc,
        g_M, be_M, g_C, be_C,
        (float*)d_out, ntok, 1.0f / (float)(B*64));
}

// Round 4
// 347.147 us; speedup vs baseline: 1.2854x; 1.2854x over previous
//
#include <hip/hip_runtime.h>
#include <math.h>

#define HDIM 256
#define NATT 100
#define PSTR 260   // proj LDS row stride (floats); 260 % 32 == 4 -> conflict-free rows

typedef __attribute__((ext_vector_type(8))) short short8v;
typedef __attribute__((ext_vector_type(4))) float f32x4;

static __device__ __forceinline__ unsigned short f2bf(float x) {
    union { float f; unsigned u; } v; v.f = x;
    const unsigned r = v.u + 0x7FFFu + ((v.u >> 16) & 1u);
    return (unsigned short)(r >> 16);
}
static __device__ __forceinline__ float bf2f(unsigned short s) {
    union { float f; unsigned u; } v; v.u = ((unsigned)s) << 16;
    return v.f;
}

// wave-internal LDS fence: all our LDS producers/consumers are same-wave,
// so lgkmcnt(0) + a scheduling fence replaces __syncthreads entirely.
#define WSYNC() do { asm volatile("s_waitcnt lgkmcnt(0)" ::: "memory"); \
                     __builtin_amdgcn_sched_barrier(0); } while (0)

// ---------------------------------------------------------------------------
// prep (43 blocks x 256): all K-parallelized (4 lanes per output)
//  blk 0..3  : wcm          blk 4..7  : wcc
//  blk 8..15 : m2m          blk 16..23: m2c
//  blk 24    : consts[0..5] + zero stats_acc
//  blk 25..32: W_at split-bf16, tiled [(n*8+k)*16+lr][32] for coalesced Ph2
//  blk 33..42: canonical first-layer weights Wc[q=m*2+x][h][32] split-bf16
// ---------------------------------------------------------------------------
__launch_bounds__(256)
__global__ void prep_kernel(
    const float* __restrict__ Ws1, const float* __restrict__ bs1,
    const float* __restrict__ Ws2, const float* __restrict__ bs2,
    const float* __restrict__ Ws1C, const float* __restrict__ bs1C,
    const float* __restrict__ Ws2C, const float* __restrict__ bs2C,
    const float* __restrict__ W2,  const float* __restrict__ b2,
    const float* __restrict__ Wd,
    const float* __restrict__ W2C, const float* __restrict__ b2C,
    const float* __restrict__ WdC,
    const float* __restrict__ W_at,
    const float* __restrict__ W_a,  const float* __restrict__ b_a,
    const float* __restrict__ W_i,  const float* __restrict__ b_i,
    const float* __restrict__ W_iC, const float* __restrict__ b_iC,
    const float* __restrict__ W_e,  const float* __restrict__ b_e,
    const float* __restrict__ W_eC, const float* __restrict__ b_eC,
    float* __restrict__ wcm, float* __restrict__ wcc,
    float* __restrict__ m2m, float* __restrict__ m2c,
    float* __restrict__ consts, float* __restrict__ stats_acc,
    unsigned short* __restrict__ WtH, unsigned short* __restrict__ WtL,
    unsigned short* __restrict__ WcH, unsigned short* __restrict__ WcL)
{
    const int tid = threadIdx.x;
    const int blk = blockIdx.x;
    if (blk < 4) {
        const int h = blk*64 + (tid>>2), l = tid&3;
        float a = 0.f;
        for (int k = l*64; k < l*64 + 64; ++k) a += Ws2[k] * Ws1[k*HDIM + h];
        a += __shfl_xor(a, 1); a += __shfl_xor(a, 2);
        if (l == 0) wcm[h] = a;
    } else if (blk < 8) {
        const int h = (blk-4)*64 + (tid>>2), l = tid&3;
        float a = 0.f;
        for (int k = l*64; k < l*64 + 64; ++k) a += Ws2C[k] * Ws1C[k*HDIM + h];
        a += __shfl_xor(a, 1); a += __shfl_xor(a, 2);
        if (l == 0) wcc[h] = a;
    } else if (blk < 16) {
        const int idx = (blk-8)*64 + (tid>>2), l = tid&3;
        const int c = idx >> 8, h = idx & 255;
        float a = 0.f;
        for (int k = l*64; k < l*64 + 64; ++k) a += Wd[c*HDIM + k] * W2[k*HDIM + h];
        a += __shfl_xor(a, 1); a += __shfl_xor(a, 2);
        if (l == 0) m2m[c*HDIM + h] = a;
    } else if (blk < 24) {
        const int idx = (blk-16)*64 + (tid>>2), l = tid&3;
        const int c = idx >> 8, h = idx & 255;
        float a = 0.f;
        for (int k = l*64; k < l*64 + 64; ++k) a += WdC[c*HDIM + k] * W2C[k*HDIM + h];
        a += __shfl_xor(a, 1); a += __shfl_xor(a, 2);
        if (l == 0) m2c[c*HDIM + h] = a;
    } else if (blk == 24) {
        __shared__ float red[6][4];
        const int k = tid;
        float p[6];
        p[0] = Ws2[k]  * bs1[k];
        p[1] = Ws2C[k] * bs1C[k];
        p[2] = Wd[k]        * b2[k];
        p[3] = Wd[HDIM+k]   * b2[k];
        p[4] = WdC[k]       * b2C[k];
        p[5] = WdC[HDIM+k]  * b2C[k];
        #pragma unroll
        for (int m = 1; m < 64; m <<= 1) {
            #pragma unroll
            for (int q = 0; q < 6; ++q) p[q] += __shfl_xor(p[q], m);
        }
        if ((tid & 63) == 0) {
            const int wv = tid >> 6;
            #pragma unroll
            for (int q = 0; q < 6; ++q) red[q][wv] = p[q];
        }
        __syncthreads();
        if (tid == 0) {
            float c0 = bs2[0], c1 = bs2C[0], c2 = 0, c3 = 0, c4 = 0, c5 = 0;
            for (int q = 0; q < 4; ++q) {
                c0 += red[0][q]; c1 += red[1][q]; c2 += red[2][q];
                c3 += red[3][q]; c4 += red[4][q]; c5 += red[5][q];
            }
            consts[0] = c0; consts[1] = c1; consts[2] = c2;
            consts[3] = c3; consts[4] = c4; consts[5] = c5;
            stats_acc[0] = 0.f; stats_acc[1] = 0.f;
            stats_acc[2] = 0.f; stats_acc[3] = 0.f;
        }
    } else if (blk < 33) {
        // W_at split-bf16, tiled so one wave-load of tile (n,k) is contiguous
        const int rbase = (blk - 25) * 14;
        const int h = tid;
        for (int rr = 0; rr < 14; ++rr) {
            const int row = rbase + rr;
            const float v = (row < NATT) ? W_at[row*HDIM + h] : 0.f;
            const int n = row >> 4, lr = row & 15;
            const int kk = h >> 5, kc = h & 31;
            const int idx = ((n*8 + kk)*16 + lr)*32 + kc;
            const unsigned short hi = f2bf(v);
            WtH[idx] = hi;
            WtL[idx] = f2bf(v - bf2f(hi));
        }
    } else {
        const int q = blk - 33;          // m*2 + x
        const int m = q >> 1, x = q & 1;
        const int h = tid;
        const float* W; const float* bias; int type;
        switch (m) {
            case 0:  W = W_a;  bias = b_a;  type = 0; break;
            case 1:  W = W_i;  bias = b_i;  type = 1; break;
            case 2:  W = W_iC; bias = b_iC; type = 2; break;
            case 3:  W = W_e;  bias = b_e;  type = 0; break;
            default: W = W_eC; bias = b_eC; type = 2; break;
        }
        float tmp[32];
        #pragma unroll
        for (int k = 0; k < 32; ++k) tmp[k] = 0.f;
        if (type == 0) {                 // x_12 cd layout: 28 cols
            const float* row = W + h*28 + x*14;
            for (int k = 0; k < 14; ++k) tmp[k] = row[k];
        } else if (type == 1) {          // f_12: [zm, cd] per half
            const float* row = W + h*30 + x*15;
            tmp[14] = row[0];
            for (int k = 0; k < 14; ++k) tmp[k] = row[1+k];
        } else {                         // fc_12: [ct_j ct_i zc_j zc_i v_j v_i]
            const float* row = W + h*30;
            for (int k = 0; k < 12; ++k) tmp[2+k] = row[x*12 + k];
            tmp[15] = row[24 + x];
            tmp[0] = row[26 + x*2];
            tmp[1] = row[27 + x*2];
        }
        tmp[16] = 0.5f * bias[h];
        const int base = (q*HDIM + h)*32;
        for (int k = 0; k < 32; ++k) {
            const unsigned short hi = f2bf(tmp[k]);
            WcH[base + k] = hi;
            WcL[base + k] = f2bf(tmp[k] - bf2f(hi));
        }
    }
}

// ---------------------------------------------------------------------------
// main: ONE WAVE PER SCENE, 4 waves/block, no __syncthreads anywhere.
// ---------------------------------------------------------------------------
__launch_bounds__(256, 2)
__global__ void main_kernel(
    const float* __restrict__ z_dyn, const float* __restrict__ z_contex,
    const float* __restrict__ z_mc,
    const float* __restrict__ b_at,
    const float* __restrict__ W_at2, const float* __restrict__ b_at2,
    const unsigned short* __restrict__ WtH, const unsigned short* __restrict__ WtL,
    const unsigned short* __restrict__ WcH, const unsigned short* __restrict__ WcL,
    const float* __restrict__ wcm,  const float* __restrict__ wcc,
    const float* __restrict__ m2m,  const float* __restrict__ m2c,
    const float* __restrict__ consts,
    float* __restrict__ pm_g, float* __restrict__ s_g, float* __restrict__ sC_g,
    float* __restrict__ um_g, float* __restrict__ uc_g,
    float* __restrict__ stats_acc, int nscene)
{
    __shared__ float s_in[4][8][16];
    alignas(16) __shared__ float proj[4][16][PSTR];   // per-wave slice
    __shared__ float pm_t[4][64];                     // [j*8+i]
    __shared__ float pmsum[4][8];

    const int tid  = threadIdx.x;
    const int w    = tid >> 6;
    const int lane = tid & 63;
    const int lr   = lane & 15;
    const int lq   = lane >> 4;
    const int scene = blockIdx.x*4 + w;
    if (scene >= nscene) return;

    // ---- Ph0: wave loads its scene's 8 tokens x 16 features ----
    {
        const int o = lane >> 3, c = lane & 7;
        const int tok = scene*8 + o;
        const float v0 = (c < 2) ? z_dyn[tok*2 + c] : z_contex[tok*12 + (c-2)];
        const int c2 = c + 8;
        const float v1 = (c2 < 14) ? z_contex[tok*12 + (c2-2)] : z_mc[tok*2 + (c2-14)];
        s_in[w][o][c]  = v0;
        s_in[w][o][c2] = v1;
    }
    WSYNC();

    // ---- feature B-fragment (kept in VGPRs for all 5 projections) ----
    short8v bfh, bfl;
    #pragma unroll
    for (int e = 0; e < 8; ++e) {
        const int k = lq*8 + e;
        float f = 0.f;
        if (lr < 8) f = (k < 16) ? s_in[w][lr][k] : (k == 16 ? 1.0f : 0.f);
        const unsigned short h16 = f2bf(f);
        bfh[e] = (short)h16;
        bfl[e] = (short)f2bf(f - bf2f(h16));
    }

    // projection: D[h][obj] for one weight matrix; 32 tile-jobs per wave
#define PROJECT(MIDX)                                                          \
    {                                                                          \
        const int mb2 = (MIDX)*2*HDIM*32;                                      \
        _Pragma("unroll 4")                                                    \
        for (int jj = 0; jj < 32; ++jj) {                                      \
            const int x = jj >> 4, t = jj & 15;                                \
            const int off = mb2 + ((x*HDIM) + t*16 + lr)*32 + lq*8;            \
            const short8v ah = *(const short8v*)&WcH[off];                     \
            const short8v al = *(const short8v*)&WcL[off];                     \
            f32x4 d = (f32x4){0.f, 0.f, 0.f, 0.f};                             \
            d = __builtin_amdgcn_mfma_f32_16x16x32_bf16(ah, bfh, d, 0, 0, 0);  \
            d = __builtin_amdgcn_mfma_f32_16x16x32_bf16(al, bfh, d, 0, 0, 0);  \
            d = __builtin_amdgcn_mfma_f32_16x16x32_bf16(ah, bfl, d, 0, 0, 0);  \
            if (lr < 8) *(f32x4*)&proj[w][x*8 + lr][t*16 + lq*4] = d;          \
        }                                                                      \
    }                                                                          \
    WSYNC();

    // ============ m=0: W_a -> presents (Ph2) ============
    PROJECT(0)
    {
        // D[a=W_at row][pair]: A=weights (tiled), B=pair features
        f32x4 acc[7][4];
        #pragma unroll
        for (int n = 0; n < 7; ++n)
            #pragma unroll
            for (int pt = 0; pt < 4; ++pt) acc[n][pt] = (f32x4){0.f,0.f,0.f,0.f};

        #pragma unroll 2
        for (int k = 0; k < 8; ++k) {
            const int kb = k*32 + lq*8;
            short8v pfh[4], pfl[4];
            #pragma unroll
            for (int pt = 0; pt < 4; ++pt) {
                const int p = pt*16 + lr;
                const int jA = p & 7, iA = p >> 3;
                const float4 vj0 = *(const float4*)&proj[w][jA][kb];
                const float4 vj1 = *(const float4*)&proj[w][jA][kb+4];
                const float4 vi0 = *(const float4*)&proj[w][8+iA][kb];
                const float4 vi1 = *(const float4*)&proj[w][8+iA][kb+4];
                const float v[8] = {vj0.x+vi0.x, vj0.y+vi0.y, vj0.z+vi0.z, vj0.w+vi0.w,
                                    vj1.x+vi1.x, vj1.y+vi1.y, vj1.z+vi1.z, vj1.w+vi1.w};
                #pragma unroll
                for (int e = 0; e < 8; ++e) {
                    const float r = fmaxf(v[e], 0.f);
                    const unsigned short h16 = f2bf(r);
                    pfh[pt][e] = (short)h16;
                    pfl[pt][e] = (short)f2bf(r - bf2f(h16));
                }
            }
            #pragma unroll
            for (int n = 0; n < 7; ++n) {
                const int wo = (n*8 + k)*512 + lr*32 + lq*8;
                const short8v wh = *(const short8v*)&WtH[wo];
                const short8v wl = *(const short8v*)&WtL[wo];
                #pragma unroll
                for (int pt = 0; pt < 4; ++pt) {
                    acc[n][pt] = __builtin_amdgcn_mfma_f32_16x16x32_bf16(wh, pfh[pt], acc[n][pt], 0, 0, 0);
                    acc[n][pt] = __builtin_amdgcn_mfma_f32_16x16x32_bf16(wl, pfh[pt], acc[n][pt], 0, 0, 0);
                    acc[n][pt] = __builtin_amdgcn_mfma_f32_16x16x32_bf16(wh, pfl[pt], acc[n][pt], 0, 0, 0);
                }
            }
        }
        // epilogue: part[pt] = sum_a W_at2[a]*tanh(D[a][pair]+b_at[a])
        float part[4] = {0.f, 0.f, 0.f, 0.f};
        #pragma unroll
        for (int n = 0; n < 7; ++n) {
            #pragma unroll
            for (int r = 0; r < 4; ++r) {
                const int a = 16*n + lq*4 + r;
                if (a < NATT) {
                    const float bat = b_at[a], w2 = W_at2[a];
                    #pragma unroll
                    for (int pt = 0; pt < 4; ++pt)
                        part[pt] += w2 * tanhf(acc[n][pt][r] + bat);
                }
            }
        }
        #pragma unroll
        for (int pt = 0; pt < 4; ++pt) {
            float s = part[pt];
            s += __shfl_xor(s, 16); s += __shfl_xor(s, 32);
            part[pt] = s;
        }
        if (lq == 0) {
            const float b2v = b_at2[0];
            #pragma unroll
            for (int pt = 0; pt < 4; ++pt) {
                const int p = pt*16 + lr;
                const int ip = p >> 3, jp = p & 7;
                const float pres = 1.f / (1.f + expf(-(part[pt] + b2v)));
                const float pmv = (ip != jp) ? pres : 0.f;
                pm_t[w][jp*8 + ip] = pmv;
                pm_g[scene*64 + jp*8 + ip] = pmv;
            }
        }
    }
    WSYNC();
    if (lane < 8) {
        const float4 q0 = *(const float4*)&pm_t[w][lane*8];
        const float4 q1 = *(const float4*)&pm_t[w][lane*8 + 4];
        pmsum[w][lane] = q0.x+q0.y+q0.z+q0.w + q1.x+q1.y+q1.z+q1.w;
    }
    WSYNC();

    const int jp = lane >> 3, ip = lane & 7;   // pair (i=ip, j=jp) per lane
    float sv, svC;

    // ============ m=1: W_i -> s ============
    PROJECT(1)
    {
        float a = 0.f;
        #pragma unroll 8
        for (int u = 0; u < 64; ++u) {
            const int h4 = u*4;
            const float4 aj = *(const float4*)&proj[w][jp][h4];
            const float4 ai = *(const float4*)&proj[w][8+ip][h4];
            const float4 wv = *(const float4*)&wcm[h4];
            a += wv.x*fmaxf(aj.x+ai.x, 0.f) + wv.y*fmaxf(aj.y+ai.y, 0.f)
               + wv.z*fmaxf(aj.z+ai.z, 0.f) + wv.w*fmaxf(aj.w+ai.w, 0.f);
        }
        sv = a + consts[0];
        s_g[scene*64 + lane] = sv;
    }
    WSYNC();

    // ============ m=2: W_iC -> sC ============
    PROJECT(2)
    {
        float a = 0.f;
        #pragma unroll 8
        for (int u = 0; u < 64; ++u) {
            const int h4 = u*4;
            const float4 aj = *(const float4*)&proj[w][jp][h4];
            const float4 ai = *(const float4*)&proj[w][8+ip][h4];
            const float4 wv = *(const float4*)&wcc[h4];
            a += wv.x*fmaxf(aj.x+ai.x, 0.f) + wv.y*fmaxf(aj.y+ai.y, 0.f)
               + wv.z*fmaxf(aj.z+ai.z, 0.f) + wv.w*fmaxf(aj.w+ai.w, 0.f);
        }
        svC = a + consts[1];
        sC_g[scene*64 + lane] = svC;
    }
    WSYNC();

    // batchnorm partial sums: wave-reduce, one atomic per scene
    {
        float a0 = sv, a1 = sv*sv, a2 = svC, a3 = svC*svC;
        #pragma unroll
        for (int m = 1; m < 64; m <<= 1) {
            a0 += __shfl_xor(a0, m); a1 += __shfl_xor(a1, m);
            a2 += __shfl_xor(a2, m); a3 += __shfl_xor(a3, m);
        }
        if (lane == 0) {
            atomicAdd(&stats_acc[0], a0); atomicAdd(&stats_acc[1], a1);
            atomicAdd(&stats_acc[2], a2); atomicAdd(&stats_acc[3], a3);
        }
    }

    // ============ m=3: W_e -> fused pm-weighted m2m dot -> u_mass ============
    PROJECT(3)
    {
        float p0 = 0.f, p1 = 0.f;
        #pragma unroll 8
        for (int u = 0; u < 64; ++u) {
            const int h4 = u*4;
            const float4 aj = *(const float4*)&proj[w][jp][h4];
            const float4 ai = *(const float4*)&proj[w][8+ip][h4];
            const float4 m0 = *(const float4*)&m2m[h4];
            const float4 m1 = *(const float4*)&m2m[HDIM + h4];
            const float e0 = fmaxf(aj.x+ai.x, 0.f), e1 = fmaxf(aj.y+ai.y, 0.f);
            const float e2 = fmaxf(aj.z+ai.z, 0.f), e3 = fmaxf(aj.w+ai.w, 0.f);
            p0 += m0.x*e0 + m0.y*e1 + m0.z*e2 + m0.w*e3;
            p1 += m1.x*e0 + m1.y*e1 + m1.z*e2 + m1.w*e3;
        }
        const float pmv = pm_t[w][jp*8 + ip];
        p0 *= pmv; p1 *= pmv;
        p0 += __shfl_xor(p0, 1); p0 += __shfl_xor(p0, 2); p0 += __shfl_xor(p0, 4);
        p1 += __shfl_xor(p1, 1); p1 += __shfl_xor(p1, 2); p1 += __shfl_xor(p1, 4);
        if (ip == 0) {
            const float ps = pmsum[w][jp];
            const float y0 = p0 + ps*consts[2];
            const float y1 = p1 + ps*consts[3];
            const float nrm = fmaxf(sqrtf(y0*y0 + y1*y1), 1e-12f);
            *(float2*)&um_g[(scene*8 + jp)*2] = make_float2(y0/nrm, y1/nrm);
        }
    }
    WSYNC();

    // ============ m=4: W_eC -> fused mask-weighted m2c dot -> u_charge ======
    PROJECT(4)
    {
        float p0 = 0.f, p1 = 0.f;
        #pragma unroll 8
        for (int u = 0; u < 64; ++u) {
            const int h4 = u*4;
            const float4 aj = *(const float4*)&proj[w][jp][h4];
            const float4 ai = *(const float4*)&proj[w][8+ip][h4];
            const float4 m0 = *(const float4*)&m2c[h4];
            const float4 m1 = *(const float4*)&m2c[HDIM + h4];
            const float e0 = fmaxf(aj.x+ai.x, 0.f), e1 = fmaxf(aj.y+ai.y, 0.f);
            const float e2 = fmaxf(aj.z+ai.z, 0.f), e3 = fmaxf(aj.w+ai.w, 0.f);
            p0 += m0.x*e0 + m0.y*e1 + m0.z*e2 + m0.w*e3;
            p1 += m1.x*e0 + m1.y*e1 + m1.z*e2 + m1.w*e3;
        }
        const float mk = (ip != jp) ? 1.f : 0.f;
        p0 *= mk; p1 *= mk;
        p0 += __shfl_xor(p0, 1); p0 += __shfl_xor(p0, 2); p0 += __shfl_xor(p0, 4);
        p1 += __shfl_xor(p1, 1); p1 += __shfl_xor(p1, 2); p1 += __shfl_xor(p1, 4);
        if (ip == 0) {
            const float y0 = p0 + 7.0f*consts[4];
            const float y1 = p1 + 7.0f*consts[5];
            const float nrm = fmaxf(sqrtf(y0*y0 + y1*y1), 1e-12f);
            *(float2*)&uc_g[(scene*8 + jp)*2] = make_float2(y0/nrm, y1/nrm);
        }
    }
#undef PROJECT
}

// ---------------------------------------------------------------------------
// final: derive batchnorm affine from global sums, then
//        scale = sum_i softplus(norm(s))*w ; out = scale*u
// ---------------------------------------------------------------------------
__launch_bounds__(256)
__global__ void final_kernel(const float* __restrict__ s_g, const float* __restrict__ sC_g,
                             const float* __restrict__ pm_g,
                             const float* __restrict__ um_g, const float* __restrict__ uc_g,
                             const float* __restrict__ stats_acc,
                             const float* __restrict__ gM, const float* __restrict__ beM,
                             const float* __restrict__ gC, const float* __restrict__ beC,
                             float* __restrict__ out, int ntok, float inv_n)
{
    const int t = blockIdx.x * blockDim.x + threadIdx.x;
    if (t >= ntok) return;
    const int j = t & 7;
    float mean = stats_acc[0] * inv_n;
    float var  = stats_acc[1] * inv_n - mean*mean;
    const float kM = gM[0] / sqrtf(var + 1e-5f);
    const float cM = beM[0] - mean*kM;
    mean = stats_acc[2] * inv_n;
    var  = stats_acc[3] * inv_n - mean*mean;
    const float kC = gC[0] / sqrtf(var + 1e-5f);
    const float cC = beC[0] - mean*kC;

    const float4 sa = *(const float4*)&s_g[t*8];
    const float4 sb = *(const float4*)&s_g[t*8 + 4];
    const float4 ca = *(const float4*)&sC_g[t*8];
    const float4 cb = *(const float4*)&sC_g[t*8 + 4];
    const float4 pa = *(const float4*)&pm_g[t*8];
    const float4 pb = *(const float4*)&pm_g[t*8 + 4];
    const float sv[8] = {sa.x,sa.y,sa.z,sa.w, sb.x,sb.y,sb.z,sb.w};
    const float cv[8] = {ca.x,ca.y,ca.z,ca.w, cb.x,cb.y,cb.z,cb.w};
    const float pv[8] = {pa.x,pa.y,pa.z,pa.w, pb.x,pb.y,pb.z,pb.w};
    float sc = 0.f, scC = 0.f, spj = 0.f;
    #pragma unroll
    for (int i = 0; i < 8; ++i) {
        const float sn = sv[i]*kM + cM;
        const float sp = fmaxf(sn, 0.f) + log1pf(expf(-fabsf(sn)));
        sc += sp * pv[i];
        const float snc = cv[i]*kC + cC;
        const float spc = fmaxf(snc, 0.f) + log1pf(expf(-fabsf(snc)));
        scC += spc;
        if (i == j) spj = spc;
    }
    scC -= spj;
    const float2 u_m = *(const float2*)&um_g[t*2];
    const float2 u_c = *(const float2*)&uc_g[t*2];
    const float m0 = sc  * u_m.x, m1 = sc  * u_m.y;
    const float c0 = scC * u_c.x, c1 = scC * u_c.y;
    *(float2*)&out[t*2]          = make_float2(m0 + c0, m1 + c1);
    *(float2*)&out[ntok*2 + t*2] = make_float2(m0, m1);
    *(float2*)&out[ntok*4 + t*2] = make_float2(c0, c1);
}

extern "C" void kernel_launch(void* const* d_in, const int* in_sizes, int n_in,
                              void* d_out, int out_size, void* d_ws, size_t ws_size,
                              hipStream_t stream) {
    const float* z_dyn    = (const float*)d_in[0];
    const float* z_contex = (const float*)d_in[1];
    const float* z_mc     = (const float*)d_in[2];
    const float* W_e   = (const float*)d_in[3];  const float* b_e   = (const float*)d_in[4];
    const float* W_i   = (const float*)d_in[5];  const float* b_i   = (const float*)d_in[6];
    const float* W_a   = (const float*)d_in[7];  const float* b_a   = (const float*)d_in[8];
    const float* W_2   = (const float*)d_in[9];  const float* b_2   = (const float*)d_in[10];
    const float* W_at  = (const float*)d_in[11]; const float* b_at  = (const float*)d_in[12];
    const float* W_at2 = (const float*)d_in[13]; const float* b_at2 = (const float*)d_in[14];
    const float* W_s1  = (const float*)d_in[15]; const float* b_s1  = (const float*)d_in[16];
    const float* W_s2  = (const float*)d_in[17]; const float* b_s2  = (const float*)d_in[18];
    const float* W_eC  = (const float*)d_in[19]; const float* b_eC  = (const float*)d_in[20];
    const float* W_iC  = (const float*)d_in[21]; const float* b_iC  = (const float*)d_in[22];
    const float* W_2C  = (const float*)d_in[23]; const float* b_2C  = (const float*)d_in[24];
    const float* W_s1C = (const float*)d_in[25]; const float* b_s1C = (const float*)d_in[26];
    const float* W_s2C = (const float*)d_in[27]; const float* b_s2C = (const float*)d_in[28];
    const float* g_M   = (const float*)d_in[29]; const float* be_M  = (const float*)d_in[30];
    const float* g_C   = (const float*)d_in[31]; const float* be_C  = (const float*)d_in[32];
    const float* W_d   = (const float*)d_in[33];
    const float* W_dC  = (const float*)d_in[34];

    const int ntok = in_sizes[0] / 2;   // 16384
    const int B = ntok / 8;             // 2048

    float* ws = (float*)d_ws;
    float* pm_g   = ws;                  // B*64 ([b][j][i])
    float* s_g    = pm_g + B*64;         // B*64
    float* sC_g   = s_g  + B*64;         // B*64
    float* um_g   = sC_g + B*64;         // ntok*2
    float* uc_g   = um_g + ntok*2;       // ntok*2
    float* wcm    = uc_g + ntok*2;       // 256
    float* wcc    = wcm + 256;           // 256
    float* m2m    = wcc + 256;           // 512
    float* m2c    = m2m + 512;           // 512
    float* consts = m2c + 512;           // 8
    float* stats_acc = consts + 8;       // 4
    unsigned short* WtH = (unsigned short*)(stats_acc + 4);  // 7*8*512 = 28672
    unsigned short* WtL = WtH + 7*8*512;
    unsigned short* WcH = WtL + 7*8*512;                     // 10*256*32 = 81920
    unsigned short* WcL = WcH + 10*HDIM*32;

    prep_kernel<<<43, 256, 0, stream>>>(
        W_s1, b_s1, W_s2, b_s2, W_s1C, b_s1C, W_s2C, b_s2C,
        W_2, b_2, W_d, W_2C, b_2C, W_dC, W_at,
        W_a, b_a, W_i, b_i, W_iC, b_iC, W_e, b_e, W_eC, b_eC,
        wcm, wcc, m2m, m2c, consts, stats_acc, WtH, WtL, WcH, WcL);

    main_kernel<<<(B + 3)/4, 256, 0, stream>>>(
        z_dyn, z_contex, z_mc,
        b_at, W_at2, b_at2,
        WtH, WtL, WcH, WcL,
        wcm, wcc, m2m, m2c, consts,
        pm_g, s_g, sC_g, um_g, uc_g, stats_acc, B);

    final_kernel<<<(ntok + 255)/256, 256, 0, stream>>>(
        s_g, sC_g, pm_g, um_g, uc_g, stats_acc,
        g_M, be_M, g_C, be_C,
        (float*)d_out, ntok, 1.0f / (float)(B*64));
}